// Round 1
// baseline (706.832 us; speedup 1.0000x reference)
//
#include <hip/hip_runtime.h>
#include <hip/hip_bf16.h>

// One triplet per 32-lane half-wave: each lane loads float4 from left row and
// right row (32 * 16B = 512B = one D=128 fp32 row, fully coalesced), dots,
// then shfl-reduces within the 32-lane group.
__global__ __launch_bounds__(256) void dot_gather_kernel(
    const int* __restrict__ trip,   // (T, 3) int32
    const float* __restrict__ emb,  // (N, 128) fp32
    float* __restrict__ out,        // (T,) fp32
    int T) {
  int gid = blockIdx.x * blockDim.x + threadIdx.x;
  int t = gid >> 5;      // 32 threads per triplet
  int lane = gid & 31;
  if (t >= T) return;

  // All 32 lanes load the same two indices; HW broadcasts same-address loads.
  long long base = 3LL * (long long)t;
  int i0 = trip[base + 0];
  int i2 = trip[base + 2];

  const float4* l = (const float4*)(emb + (long long)i0 * 128);
  const float4* r = (const float4*)(emb + (long long)i2 * 128);
  float4 a = l[lane];
  float4 b = r[lane];
  float s = a.x * b.x + a.y * b.y + a.z * b.z + a.w * b.w;

  // Reduce across the 32-lane group.
  #pragma unroll
  for (int off = 16; off > 0; off >>= 1)
    s += __shfl_down(s, off, 32);

  if (lane == 0) out[t] = s;
}

extern "C" void kernel_launch(void* const* d_in, const int* in_sizes, int n_in,
                              void* d_out, int out_size, void* d_ws, size_t ws_size,
                              hipStream_t stream) {
  const int* trip = (const int*)d_in[0];     // triplets (T,3) int32
  const float* emb = (const float*)d_in[1];  // node_emb (N,128) fp32
  float* out = (float*)d_out;

  int T = in_sizes[0] / 3;
  long long total_threads = 32LL * T;
  int block = 256;
  long long grid = (total_threads + block - 1) / block;

  dot_gather_kernel<<<(int)grid, block, 0, stream>>>(trip, emb, out, T);
}

// Round 2
// 698.251 us; speedup vs baseline: 1.0123x; 1.0123x over previous
//
#include <hip/hip_runtime.h>
#include <hip/hip_bf16.h>

// U triplets per 32-lane group. Load all 2*U indices first, then issue all
// 2*U row-gathers (float4/lane, 32 lanes = 512B row, fully coalesced) so the
// wave has 2*U vmem ops in flight, then reduce each dot with 5 shuffles.
constexpr int U = 8;

__global__ __launch_bounds__(256) void dot_gather_kernel(
    const int* __restrict__ trip,   // (T, 3) int32
    const float* __restrict__ emb,  // (N, 128) fp32
    float* __restrict__ out,        // (T,) fp32
    int T) {
  int gid = blockIdx.x * blockDim.x + threadIdx.x;
  int group = gid >> 5;   // 32-lane group id
  int lane = gid & 31;
  long long t0 = (long long)group * U;
  if (t0 >= T) return;

  // Gather indices for U triplets (broadcast loads within the group; the
  // triplet array is streamed contiguously across neighboring groups -> L2 hits).
  int iL[U], iR[U];
  #pragma unroll
  for (int u = 0; u < U; ++u) {
    long long t = (t0 + u < T) ? (t0 + u) : (long long)(T - 1);
    iL[u] = trip[3 * t];
    iR[u] = trip[3 * t + 2];
  }

  // Issue all row gathers back-to-back: 2*U outstanding float4 loads/thread.
  float4 a[U], b[U];
  #pragma unroll
  for (int u = 0; u < U; ++u) {
    a[u] = ((const float4*)(emb + (long long)iL[u] * 128))[lane];
    b[u] = ((const float4*)(emb + (long long)iR[u] * 128))[lane];
  }

  // Dot + 32-lane reduction per triplet.
  #pragma unroll
  for (int u = 0; u < U; ++u) {
    float s = a[u].x * b[u].x + a[u].y * b[u].y + a[u].z * b[u].z + a[u].w * b[u].w;
    #pragma unroll
    for (int off = 16; off > 0; off >>= 1)
      s += __shfl_down(s, off, 32);
    if (lane == 0 && t0 + u < T) out[t0 + u] = s;
  }
}

extern "C" void kernel_launch(void* const* d_in, const int* in_sizes, int n_in,
                              void* d_out, int out_size, void* d_ws, size_t ws_size,
                              hipStream_t stream) {
  const int* trip = (const int*)d_in[0];     // triplets (T,3) int32
  const float* emb = (const float*)d_in[1];  // node_emb (N,128) fp32
  float* out = (float*)d_out;

  int T = in_sizes[0] / 3;
  long long groups = ((long long)T + U - 1) / U;
  long long total_threads = groups * 32;
  int block = 256;
  long long grid = (total_threads + block - 1) / block;

  dot_gather_kernel<<<(int)grid, block, 0, stream>>>(trip, emb, out, T);
}